// Round 5
// baseline (199.566 us; speedup 1.0000x reference)
//
#include <hip/hip_runtime.h>

// HashGridPositionalEncoding4D — round 5: round-3 structure + NON-TEMPORAL
// table gathers (single-lever A/B vs round 3).
//
// Evidence so far: rounds 1/3/4 (naive, ILP=4+nt streams, +fences+XCD split)
// all pinned at 135-148 us profiled. FETCH_SIZE = compulsory 159 MB. The
// invariant is 16.78M random 8B gathers = ~5 cy/lane-request/CU. Theory:
// every gather misses L1 and pays the allocate/fill/evict path (thrashes all
// 512 L1 lines ~128x per CU, zero reuse). nt-hint the gathers to skip L1
// allocation -> raw lookup/forward path.

#define NPOINTS (8 * 131072)
#define TOTAL_ITEMS (NPOINTS * 8)      // 8,388,608
#define ILP 4
#define STRIDE (TOTAL_ITEMS / ILP)     // 2,097,152
#define TABLE_MASK 65535u

typedef float v4f __attribute__((ext_vector_type(4)));
typedef float v2f __attribute__((ext_vector_type(2)));

__global__ __launch_bounds__(256) void hashgrid4d_kernel(
    const float* __restrict__ x,
    const float* __restrict__ coords,
    const float* __restrict__ tables,
    const float* __restrict__ freq_bands,
    float* __restrict__ out)
{
    const int tid  = blockIdx.x * blockDim.x + threadIdx.x;
    const int slot = tid & 7;          // same for all ILP items (STRIDE % 8 == 0)

    const float f0 = freq_bands[slot * 2 + 0];
    const float f1 = freq_bands[slot * 2 + 1];

    // PRIMES rounded to float32, identical to np.array(..., dtype=np.float32)
    const float P1 = 2654435761.0f;
    const float P2 = 805459861.0f;
    const float P3 = 3674653429.0f;

    // ---- 1) coords loads ----
    v4f c[ILP];
    #pragma unroll
    for (int k = 0; k < ILP; ++k) {
        const int p = (tid + k * STRIDE) >> 3;
        c[k] = *reinterpret_cast<const v4f*>(coords + (size_t)p * 4);
    }

    // ---- 2) hash + gathers (NON-TEMPORAL: no L1 allocate, zero reuse) ----
    v2f ft[ILP][2];
    #pragma unroll
    for (int k = 0; k < ILP; ++k) {
        const float c0 = fminf(fmaxf(c[k].x, 0.0f), 1.0f);
        const float c1 = fminf(fmaxf(c[k].y, 0.0f), 1.0f);
        const float c2 = fminf(fmaxf(c[k].z, 0.0f), 1.0f);
        const float c3 = fminf(fmaxf(c[k].w, 0.0f), 1.0f);
        #pragma unroll
        for (int j = 0; j < 2; ++j) {
            const float f = j ? f1 : f0;
            const int   l = slot * 2 + j;
            // v = (c*f)*P : two separate rn-multiplies, no FMA/reassoc (bit-
            // exact vs numpy). mod 2^32 + astype(uint32) of non-negative f32
            // == trunc to u64 then wrap to u32 (fmod is exact in IEEE).
            const float t0 = __fmul_rn(c0, f);
            const float t1 = __fmul_rn(c1, f);
            const float t2 = __fmul_rn(c2, f);
            const float t3 = __fmul_rn(c3, f);
            const unsigned int h0 = (unsigned int)(unsigned long long)t0;
            const unsigned int h1 = (unsigned int)(unsigned long long)__fmul_rn(t1, P1);
            const unsigned int h2 = (unsigned int)(unsigned long long)__fmul_rn(t2, P2);
            const unsigned int h3 = (unsigned int)(unsigned long long)__fmul_rn(t3, P3);
            const unsigned int idx = (h0 ^ h1 ^ h2 ^ h3) & TABLE_MASK;
            ft[k][j] = __builtin_nontemporal_load(reinterpret_cast<const v2f*>(
                tables + (((size_t)l << 16) + idx) * 2));
        }
    }

    // ---- 3) x loads (non-temporal stream) ----
    v4f xv[ILP];
    #pragma unroll
    for (int k = 0; k < ILP; ++k) {
        const size_t off = (size_t)(tid + k * STRIDE) * 4;
        xv[k] = __builtin_nontemporal_load(
            reinterpret_cast<const v4f*>(x + off));
    }

    // ---- 4) add + non-temporal stores ----
    #pragma unroll
    for (int k = 0; k < ILP; ++k) {
        const size_t off = (size_t)(tid + k * STRIDE) * 4;
        v4f o;
        o.x = xv[k].x + ft[k][0].x;
        o.y = xv[k].y + ft[k][0].y;
        o.z = xv[k].z + ft[k][1].x;
        o.w = xv[k].w + ft[k][1].y;
        __builtin_nontemporal_store(o, reinterpret_cast<v4f*>(out + off));
    }
}

extern "C" void kernel_launch(void* const* d_in, const int* in_sizes, int n_in,
                              void* d_out, int out_size, void* d_ws, size_t ws_size,
                              hipStream_t stream) {
    const float* x          = (const float*)d_in[0];
    const float* coords     = (const float*)d_in[1];
    const float* tables     = (const float*)d_in[2];
    const float* freq_bands = (const float*)d_in[3];
    float* out              = (float*)d_out;

    const int block = 256;
    const int grid  = STRIDE / block;  // 8192 blocks, ILP=4 items per thread

    hashgrid4d_kernel<<<grid, block, 0, stream>>>(x, coords, tables, freq_bands, out);
}

// Round 6
// 124.702 us; speedup vs baseline: 1.6003x; 1.6003x over previous
//
#include <hip/hip_runtime.h>

// HashGridPositionalEncoding4D — round 6.
//   Revert round-5 nt-gathers (proved L2 was serving tables: FETCH 159->373MB,
//   dur 135->208us). New levers:
//   (a) inline-asm volatile gathers: forces all 8 table loads per thread into
//       flight simultaneously (compiler re-fissioned every source-level
//       attempt back to VGPR=24). One explicit s_waitcnt vmcnt(0) +
//       sched_barrier(0) before consumption (guide rule #18).
//   (b) sc0 flag on the gathers: read at L2 coherence point WITHOUT L1
//       allocation (unlike nt, keeps L2 allocate). Tests the theory that the
//       L1 allocate/fill/evict path caps per-CU miss concurrency (~74 lines
//       in flight implied by 347 cy/gather-instr across rounds 1/3/4).
//
// Mapping unchanged from round 3: 8 lane-slots per point, slot j -> levels
// 2j,2j+1 -> output floats [4j,4j+4). ILP=4 items per thread, stride TOTAL/4.
// x/out non-temporal (kept FETCH at compulsory 159 MB).

#define NPOINTS (8 * 131072)
#define TOTAL_ITEMS (NPOINTS * 8)      // 8,388,608
#define ILP 4
#define STRIDE (TOTAL_ITEMS / ILP)     // 2,097,152
#define TABLE_MASK 65535u

typedef float v4f __attribute__((ext_vector_type(4)));
typedef float v2f __attribute__((ext_vector_type(2)));

__global__ __launch_bounds__(256) void hashgrid4d_kernel(
    const float* __restrict__ x,
    const float* __restrict__ coords,
    const float* __restrict__ tables,
    const float* __restrict__ freq_bands,
    float* __restrict__ out)
{
    const int tid  = blockIdx.x * blockDim.x + threadIdx.x;
    const int slot = tid & 7;          // same for all ILP items (STRIDE % 8 == 0)

    const float f0 = freq_bands[slot * 2 + 0];
    const float f1 = freq_bands[slot * 2 + 1];

    // PRIMES rounded to float32, identical to np.array(..., dtype=np.float32)
    const float P1 = 2654435761.0f;
    const float P2 = 805459861.0f;
    const float P3 = 3674653429.0f;

    // ---- 1) coords loads ----
    v4f c[ILP];
    #pragma unroll
    for (int k = 0; k < ILP; ++k) {
        const int p = (tid + k * STRIDE) >> 3;
        c[k] = *reinterpret_cast<const v4f*>(coords + (size_t)p * 4);
    }

    // ---- 2) hash -> gather addresses ----
    const float* ga[ILP][2];
    #pragma unroll
    for (int k = 0; k < ILP; ++k) {
        const float c0 = fminf(fmaxf(c[k].x, 0.0f), 1.0f);
        const float c1 = fminf(fmaxf(c[k].y, 0.0f), 1.0f);
        const float c2 = fminf(fmaxf(c[k].z, 0.0f), 1.0f);
        const float c3 = fminf(fmaxf(c[k].w, 0.0f), 1.0f);
        #pragma unroll
        for (int j = 0; j < 2; ++j) {
            const float f = j ? f1 : f0;
            const int   l = slot * 2 + j;
            // v = (c*f)*P : two separate rn-multiplies, no FMA/reassoc (bit-
            // exact vs numpy). mod 2^32 + astype(uint32) of non-negative f32
            // == trunc to u64 then wrap to u32 (fmod is exact in IEEE).
            const float t0 = __fmul_rn(c0, f);
            const float t1 = __fmul_rn(c1, f);
            const float t2 = __fmul_rn(c2, f);
            const float t3 = __fmul_rn(c3, f);
            const unsigned int h0 = (unsigned int)(unsigned long long)t0;
            const unsigned int h1 = (unsigned int)(unsigned long long)__fmul_rn(t1, P1);
            const unsigned int h2 = (unsigned int)(unsigned long long)__fmul_rn(t2, P2);
            const unsigned int h3 = (unsigned int)(unsigned long long)__fmul_rn(t3, P3);
            const unsigned int idx = (h0 ^ h1 ^ h2 ^ h3) & TABLE_MASK;
            ga[k][j] = tables + (((size_t)l << 16) + idx) * 2;
        }
    }

    // ---- 3) issue ALL 8 gathers (volatile asm: cannot be re-fissioned).
    //         sc0 = no L1 allocate, L2 allocate kept. ----
    v2f ft[ILP][2];
    #pragma unroll
    for (int k = 0; k < ILP; ++k) {
        #pragma unroll
        for (int j = 0; j < 2; ++j) {
            asm volatile("global_load_dwordx2 %0, %1, off sc0"
                         : "=v"(ft[k][j]) : "v"(ga[k][j]));
        }
    }

    // ---- 4) x loads (non-temporal stream), issued while gathers in flight ----
    v4f xv[ILP];
    #pragma unroll
    for (int k = 0; k < ILP; ++k) {
        const size_t off = (size_t)(tid + k * STRIDE) * 4;
        xv[k] = __builtin_nontemporal_load(reinterpret_cast<const v4f*>(x + off));
    }

    // ---- 5) drain all in-flight loads, then consume (rule #18 fence) ----
    asm volatile("s_waitcnt vmcnt(0)" ::: "memory");
    __builtin_amdgcn_sched_barrier(0);

    #pragma unroll
    for (int k = 0; k < ILP; ++k) {
        const size_t off = (size_t)(tid + k * STRIDE) * 4;
        v4f o;
        o.x = xv[k].x + ft[k][0].x;
        o.y = xv[k].y + ft[k][0].y;
        o.z = xv[k].z + ft[k][1].x;
        o.w = xv[k].w + ft[k][1].y;
        __builtin_nontemporal_store(o, reinterpret_cast<v4f*>(out + off));
    }
}

extern "C" void kernel_launch(void* const* d_in, const int* in_sizes, int n_in,
                              void* d_out, int out_size, void* d_ws, size_t ws_size,
                              hipStream_t stream) {
    const float* x          = (const float*)d_in[0];
    const float* coords     = (const float*)d_in[1];
    const float* tables     = (const float*)d_in[2];
    const float* freq_bands = (const float*)d_in[3];
    float* out              = (float*)d_out;

    const int block = 256;
    const int grid  = STRIDE / block;  // 8192 blocks, ILP=4 items per thread

    hashgrid4d_kernel<<<grid, block, 0, stream>>>(x, coords, tables, freq_bands, out);
}